// Round 8
// baseline (2147.174 us; speedup 1.0000x reference)
//
#include <hip/hip_runtime.h>
#include <cstddef>
#include <cstdint>

#define B_ 32
#define T_ 1024
#define IN_ 256
#define H_ 512
#define O_ 256
#define DT_ 0.1f

typedef _Float16 f16x8 __attribute__((ext_vector_type(8)));
typedef float f32x4 __attribute__((ext_vector_type(4)));

// ---------------------------------------------------------------------------
// Generic fp32 GEMM: C[m][n] = sum_k A[m][k] * Bw[n][k],  M = 32768 fixed.
// ---------------------------------------------------------------------------
template<int N, int K, bool SWA, bool SWC>
__global__ __launch_bounds__(256, 4) void gemm128(const float* __restrict__ A,
                                                  const float* __restrict__ Bw,
                                                  float* __restrict__ C) {
    __shared__ float al[32][132];
    __shared__ float bl[32][132];
    const int tid = threadIdx.x;
    const int m0 = blockIdx.x * 128;
    const int n0 = blockIdx.y * 128;
    const int tx = tid & 15;
    const int ty = tid >> 4;
    float acc[8][8] = {};

    const int lrow = tid >> 3;
    const int kk = (tid & 7) * 4;

    for (int kc = 0; kc < K; kc += 32) {
        __syncthreads();
#pragma unroll
        for (int p = 0; p < 4; ++p) {
            const int row = lrow + p * 32;
            const int m = m0 + row;
            const size_t aoff = SWA ? ((size_t)((m & 31) * T_ + (m >> 5)) * K)
                                    : ((size_t)m * K);
            const float4 v = *(const float4*)(A + aoff + kc + kk);
            al[kk + 0][row] = v.x; al[kk + 1][row] = v.y;
            al[kk + 2][row] = v.z; al[kk + 3][row] = v.w;
        }
#pragma unroll
        for (int p = 0; p < 4; ++p) {
            const int row = lrow + p * 32;
            const float4 v = *(const float4*)(Bw + (size_t)(n0 + row) * K + kc + kk);
            bl[kk + 0][row] = v.x; bl[kk + 1][row] = v.y;
            bl[kk + 2][row] = v.z; bl[kk + 3][row] = v.w;
        }
        __syncthreads();
#pragma unroll
        for (int k = 0; k < 32; ++k) {
            float av[8], bv[8];
            *(float4*)&av[0] = *(const float4*)&al[k][ty * 8];
            *(float4*)&av[4] = *(const float4*)&al[k][ty * 8 + 4];
            *(float4*)&bv[0] = *(const float4*)&bl[k][tx * 8];
            *(float4*)&bv[4] = *(const float4*)&bl[k][tx * 8 + 4];
#pragma unroll
            for (int i = 0; i < 8; ++i)
#pragma unroll
                for (int j = 0; j < 8; ++j)
                    acc[i][j] = fmaf(av[i], bv[j], acc[i][j]);
        }
    }
#pragma unroll
    for (int i = 0; i < 8; ++i) {
        const int m = m0 + ty * 8 + i;
        const size_t coff = SWC ? ((size_t)((m & 31) * T_ + (m >> 5)) * N)
                                : ((size_t)m * N);
        const float4 v0 = make_float4(acc[i][0], acc[i][1], acc[i][2], acc[i][3]);
        const float4 v1 = make_float4(acc[i][4], acc[i][5], acc[i][6], acc[i][7]);
        *(float4*)(C + coff + n0 + tx * 8) = v0;
        *(float4*)(C + coff + n0 + tx * 8 + 4) = v1;
    }
}

// ---------------------------------------------------------------------------
// K2: a_coef[t][h] = 1 - DT / softplus(tc[h] + 0.1 * mean_b |sensory[t][b][h]|)
// ---------------------------------------------------------------------------
__global__ __launch_bounds__(512) void tau_kernel(const float* __restrict__ sens,
                                                  const float* __restrict__ tc,
                                                  float* __restrict__ acoef) {
    const int t = blockIdx.x;
    const int h = threadIdx.x;
    float s = 0.f;
#pragma unroll 8
    for (int b = 0; b < B_; ++b)
        s += fabsf(sens[((size_t)t * B_ + b) * H_ + h]);
    const float x = tc[h] + 0.1f * (s * (1.f / 32.f));
    const float sp = fmaxf(x, 0.f) + log1pf(expf(-fabsf(x)));
    acoef[(size_t)t * H_ + h] = 1.f - DT_ / sp;
}

// ---------------------------------------------------------------------------
// K3: serial scan via MFMA. 32 WGs (1/batch) x 512 threads (8 waves, 2/SIMD).
// Wave w owns rows 64w..64w+63 over ALL 512 k: 4 row-tiles(16) x 16 k-tiles(32)
// of v_mfma_f32_16x16x32_f16 per step. W-frags: k-tiles 0..11 in AGPRs
// (192 regs, MFMA reads AGPR natively -> ZERO move insts), k-tiles 12..15
// streamed from LDS (128 KB, per-lane b128 full rate). B-operand: h[512] f16
// in LDS, 1 broadcast b128 per k-tile; only B col 0 is real (cols 1..15
// multiply into D cols we never read). A/B k-mapping assumption is safe by
// k-permutation invariance (same map used for both operands).
// C/D layout (m89-verified): row=(lane>>4)*4+reg, col=lane&15.
// Epilogue: lanes l&15==0 hold rec col; one predicated b128 pred-write per
// row-tile; no cross-wave reduction (each wave did full k). 2 lgkm-only
// barriers/step; sensH global store stays in flight (proven R7).
// ---------------------------------------------------------------------------
#define WLDS_BYTES 131072
#define PRED_OFF   WLDS_BYTES
#define H2S_OFF    (WLDS_BYTES + 2048)
#define SMEM_TOT   (WLDS_BYTES + 2048 + 1024)

#define BARRIER_LGKM() asm volatile("s_waitcnt lgkmcnt(0)\n\ts_barrier" ::: "memory")
#define MFMA16(a, b, c) __builtin_amdgcn_mfma_f32_16x16x32_f16(a, b, c, 0, 0, 0)

__global__ __attribute__((amdgpu_flat_work_group_size(512, 512),
                          amdgpu_waves_per_eu(2, 2)))
void scan_kernel(const float* __restrict__ Wr, const float* __restrict__ acoef,
                 const float* __restrict__ bias, float* sensH,
                 float* __restrict__ finalh) {
    extern __shared__ char smem[];
    float* pred   = (float*)(smem + PRED_OFF);        // [512]
    _Float16* h2s = (_Float16*)(smem + H2S_OFF);      // [512]

    const int tid  = threadIdx.x;
    const int b    = blockIdx.x;
    const int lane = tid & 63;
    const int w    = tid >> 6;
    const int lm   = lane & 15;      // A-row / D-col index
    const int lq   = lane >> 4;      // k-high / D-row-quad index

    // --- one-time: W frags. kt 0..11 -> AGPR arrays; kt 12..15 -> LDS ---
    f16x8 wf0[12], wf1[12], wf2[12], wf3[12];
#pragma unroll
    for (int kt = 0; kt < 16; ++kt) {
#pragma unroll
        for (int rt = 0; rt < 4; ++rt) {
            const int row  = w * 64 + rt * 16 + lm;
            const int col0 = kt * 32 + lq * 8;
            const float* p = Wr + (size_t)row * H_ + col0;
            const float4 v0 = *(const float4*)p;
            const float4 v1 = *(const float4*)(p + 4);
            f16x8 f;
            f[0] = (_Float16)v0.x; f[1] = (_Float16)v0.y;
            f[2] = (_Float16)v0.z; f[3] = (_Float16)v0.w;
            f[4] = (_Float16)v1.x; f[5] = (_Float16)v1.y;
            f[6] = (_Float16)v1.z; f[7] = (_Float16)v1.w;
            if (kt < 12) {
                if      (rt == 0) wf0[kt] = f;
                else if (rt == 1) wf1[kt] = f;
                else if (rt == 2) wf2[kt] = f;
                else              wf3[kt] = f;
            } else {
                *(f16x8*)(smem + ((((kt - 12) * 8 + w) * 4 + rt) * 64 + lane) * 16) = f;
            }
        }
    }

    if (tid < 256) ((float*)h2s)[tid] = 0.f;   // zero h2s (512 f16 = 256 f32)
    float h_reg = 0.f;
    const float bias_r = bias[tid];
    float s_cur = sensH[(size_t)b * H_ + tid];
    float a_cur = acoef[tid];
    __syncthreads();   // one-time full drain: W-LDS + h2s visible

    // LDS read helpers (byte offsets)
    const int bq_base = H2S_OFF + lq * 16;                   // + kt*64
    const int wl_base = (w * 4 * 64 + lane) * 16;            // + (kt-12)*8*4*1024 + rt*1024

#define LDB(kt) (*(const f16x8*)(smem + bq_base + (kt) * 64))
#define LDW(kt, rt) (*(const f16x8*)(smem + ((kt) - 12) * 32768 + wl_base + (rt) * 1024))

    for (int t = 0; t < T_; ++t) {
        const int tn = (t < T_ - 1) ? t + 1 : t;
        const float s_nxt = sensH[((size_t)tn * B_ + b) * H_ + tid];
        const float a_nxt = acoef[(size_t)tn * H_ + tid];

        f32x4 D0 = {0.f, 0.f, 0.f, 0.f};
        f32x4 D1 = {0.f, 0.f, 0.f, 0.f};
        f32x4 D2 = {0.f, 0.f, 0.f, 0.f};
        f32x4 D3 = {0.f, 0.f, 0.f, 0.f};

        // ---- k-tiles 0..11: W from AGPR (no LDS dependency beyond B)
        f16x8 bcur = LDB(0);
#pragma unroll
        for (int kt = 0; kt < 12; ++kt) {
            const f16x8 bnxt = LDB(kt + 1);
            D0 = MFMA16(wf0[kt], bcur, D0);
            D1 = MFMA16(wf1[kt], bcur, D1);
            D2 = MFMA16(wf2[kt], bcur, D2);
            D3 = MFMA16(wf3[kt], bcur, D3);
            bcur = bnxt;
        }
        // ---- k-tiles 12..15: W streamed from LDS (prefetched 1 tile ahead)
        {
            f16x8 u0 = LDW(12, 0), u1 = LDW(12, 1), u2 = LDW(12, 2), u3 = LDW(12, 3);
#pragma unroll
            for (int kt = 12; kt < 16; ++kt) {
                f16x8 n0, n1, n2, n3, bnxt;
                if (kt < 15) {
                    bnxt = LDB(kt + 1);
                    n0 = LDW(kt + 1, 0); n1 = LDW(kt + 1, 1);
                    n2 = LDW(kt + 1, 2); n3 = LDW(kt + 1, 3);
                }
                D0 = MFMA16(u0, bcur, D0);
                D1 = MFMA16(u1, bcur, D1);
                D2 = MFMA16(u2, bcur, D2);
                D3 = MFMA16(u3, bcur, D3);
                if (kt < 15) { u0 = n0; u1 = n1; u2 = n2; u3 = n3; bcur = bnxt; }
            }
        }

        // ---- epilogue: col 0 lanes write rec rows (row=(lq)*4+reg)
        if (lm == 0) {
            float* pb = pred + w * 64 + lq * 4;
            *(f32x4*)(pb +  0) = D0;
            *(f32x4*)(pb + 16) = D1;
            *(f32x4*)(pb + 32) = D2;
            *(f32x4*)(pb + 48) = D3;
        }
        BARRIER_LGKM();

        // ---- update: thread owns h[tid]
        {
            const float rec = pred[tid];
            const float act = tanhf(s_cur + rec + bias_r);
            h_reg = a_cur * h_reg + DT_ * act;
            sensH[((size_t)t * B_ + b) * H_ + tid] = h_reg;  // stays in flight
            h2s[tid] = (_Float16)h_reg;                      // next step's B
            s_cur = s_nxt;
            a_cur = a_nxt;
        }
        BARRIER_LGKM();
    }
    finalh[(size_t)b * H_ + tid] = h_reg;
#undef LDB
#undef LDW
}

// ---------------------------------------------------------------------------
extern "C" void kernel_launch(void* const* d_in, const int* in_sizes, int n_in,
                              void* d_out, int out_size, void* d_ws, size_t ws_size,
                              hipStream_t stream) {
    const float* x    = (const float*)d_in[0];
    const float* Win  = (const float*)d_in[1];
    const float* Wr   = (const float*)d_in[2];
    const float* tc   = (const float*)d_in[3];
    const float* Wo   = (const float*)d_in[4];
    const float* bias = (const float*)d_in[5];
    float* out = (float*)d_out;

    float* sensH = (float*)d_ws;                               // [T*B][H], later hiddens
    float* acoef = sensH + (size_t)T_ * B_ * H_;               // [T][H]
    const size_t need = ((size_t)T_ * B_ * H_ + (size_t)T_ * H_) * sizeof(float);
    if (ws_size < need) return;

    (void)hipFuncSetAttribute((const void*)scan_kernel,
                              hipFuncAttributeMaxDynamicSharedMemorySize, SMEM_TOT);

    // K1: sensory[t*32+b][h] = sum_i x[b][t][i] * Win[h][i]
    {
        dim3 grid(32768 / 128, H_ / 128);
        hipLaunchKernelGGL((gemm128<H_, IN_, true, false>), grid, dim3(256), 0, stream,
                           x, Win, sensH);
    }
    // K2: a_coef
    hipLaunchKernelGGL(tau_kernel, dim3(T_), dim3(H_), 0, stream, sensH, tc, acoef);
    // K3: scan
    hipLaunchKernelGGL(scan_kernel, dim3(B_), dim3(512), SMEM_TOT, stream,
                       Wr, acoef, bias, sensH, out + (size_t)B_ * T_ * O_);
    // K4: out[b][t][o] = sum_h hiddens[t*32+b][h] * Wo[o][h]
    {
        dim3 grid(32768 / 128, O_ / 128);
        hipLaunchKernelGGL((gemm128<O_, H_, false, true>), grid, dim3(256), 0, stream,
                           sensH, Wo, out);
    }
}